// Round 20
// baseline (2413.728 us; speedup 1.0000x reference)
//
#include <hip/hip_runtime.h>
#include <stdint.h>

#pragma clang fp contract(off)

constexpr int B_ = 1024, IN_ = 2048, H0_ = 1024, H1_ = 1024, OUT_ = 512;
constexpr int TC = 2;        // timesteps per chunk
constexpr int NCHUNK = 8;    // 16 / TC
constexpr int PQ = 512;      // K-panel width (bitwise-verified in round 16)

// Arithmetic fence: forces the f32 value to materialize — kills FMA contraction
// and reassociation across this point even under -ffp-contract=fast.
static __device__ __forceinline__ float fencef(float x) {
  asm volatile("" : "+v"(x));
  return x;
}

// ---------- transpose chunk: X[b][i][t0+tc] -> Xt[tc*B + b][i] (f32) ----------
__global__ void transpose_x2(const float* __restrict__ X, float* __restrict__ Xt, int t0) {
  int idx = blockIdx.x * 256 + threadIdx.x;  // b*IN + i
  int b = idx >> 11, i = idx & (IN_ - 1);
  float2 v = *(const float2*)(X + (size_t)idx * 16 + t0);
  Xt[(size_t)b * IN_ + i] = v.x;
  Xt[(size_t)(B_ + b) * IN_ + i] = v.y;
}

// ---------- f32 NT GEMM, ONE 512-panel per block, 8x8 micro-tile ----------
// Panel p of C[M][N]: acc = sum_{k=512p..512p+511} fma(A[m,k], B[n,k], acc),
// single accumulator, ascending k, f32 FMA — bitwise-identical chain to the
// round-16/17 passing kernels. r19 showed the kernel is LDS-read-bound
// (1.5 B/FMA = 123 us = measured); 8x8 micro-tile cuts it to 1.0 B/FMA.
// BM=128, BN=64, BK=32; 128 threads (2 waves); 8x8 micro-tile.
__global__ __launch_bounds__(128) void gemm_panel(
    const float* __restrict__ A, const float* __restrict__ Bw,
    float* __restrict__ ZP, size_t pstride, int Ntiles, int K, int N) {
  __shared__ float As[32][132];  // k-major, padded (k-row stride 132f = 4 banks)
  __shared__ float Bs[32][68];

  // bijective XCD swizzle (all grids here are multiples of 8)
  int bid = blockIdx.x, cpx = gridDim.x >> 3;
  int wg = (bid & 7) * cpx + (bid >> 3);
  int tpp = (gridDim.x / ((K + PQ - 1) / PQ));     // tiles per panel = Mt*Nt
  int p = wg / tpp, r = wg - p * tpp;
  int bm = r / Ntiles, bn = r - bm * Ntiles;

  int tid = threadIdx.x;
  int tx = tid & 7, ty = tid >> 3;         // micro-tile: cols tx*8.., rows ty*8..
  int rb = tid >> 1, cb = (tid & 1) * 16;  // B staging: row 0..63, 16-col half

  float acc[8][8] = {};   // THE panel chain accumulators (init 0, ascending k)
  const size_t rowA = (size_t)(bm * 128 + tid) * K + p * PQ;  // A staging: 1 row/thread
  const size_t rowB = (size_t)(bn * 64 + rb) * K + p * PQ;

  for (int kk = 0; kk < PQ; kk += 32) {
    float4 av[8], bv[4];
#pragma unroll
    for (int q = 0; q < 8; ++q)
      av[q] = *(const float4*)(A + rowA + kk + q * 4);
#pragma unroll
    for (int q = 0; q < 4; ++q)
      bv[q] = *(const float4*)(Bw + rowB + kk + cb + q * 4);
    __syncthreads();  // previous-tile reads done before overwrite
#pragma unroll
    for (int q = 0; q < 8; ++q) {
      As[q * 4 + 0][tid] = av[q].x;
      As[q * 4 + 1][tid] = av[q].y;
      As[q * 4 + 2][tid] = av[q].z;
      As[q * 4 + 3][tid] = av[q].w;
    }
#pragma unroll
    for (int q = 0; q < 4; ++q) {
      Bs[cb + q * 4 + 0][rb] = bv[q].x;
      Bs[cb + q * 4 + 1][rb] = bv[q].y;
      Bs[cb + q * 4 + 2][rb] = bv[q].z;
      Bs[cb + q * 4 + 3][rb] = bv[q].w;
    }
    __syncthreads();  // tile ready
#pragma unroll
    for (int k = 0; k < 32; ++k) {   // ascending k — order is frozen
      float ar[8], br[8];
#pragma unroll
      for (int i = 0; i < 8; ++i) ar[i] = As[k][ty * 8 + i];
#pragma unroll
      for (int j = 0; j < 8; ++j) br[j] = Bs[k][tx * 8 + j];
#pragma unroll
      for (int i = 0; i < 8; ++i)
#pragma unroll
        for (int j = 0; j < 8; ++j)
          acc[i][j] = __builtin_fmaf(ar[i], br[j], acc[i][j]);
    }
  }
  float* Cb = ZP + p * pstride + (size_t)(bm * 128 + ty * 8) * N + bn * 64 + tx * 8;
#pragma unroll
  for (int i = 0; i < 8; ++i)
#pragma unroll
    for (int j = 0; j < 8; ++j)
      Cb[(size_t)i * N + j] = acc[i][j];
}

// ---------- FLOAT32 LIF over TC steps + in-order panel combine, fenced ----------
// z = (((0 + P0) + P1) + ...) — bitwise-identical to round 16's creg loop.
template <int NP>
__global__ void lif_chunk(const float* __restrict__ ZP, size_t pstride,
                          const float* __restrict__ bias,
                          float* __restrict__ stC, float* __restrict__ stV,
                          float* __restrict__ stU, float* __restrict__ Sout,
                          float* __restrict__ accB, float* __restrict__ Out,
                          int ncol, int first, int last) {
  int gid = blockIdx.x * 256 + threadIdx.x;  // b*ncol + n
  int n = gid & (ncol - 1);
  float bn = bias[n];
  float c, v, u, s, acc;
  if (first) {
    c = 0.f; v = 0.f; u = 0.f; s = 0.f; acc = 0.f;
  } else {
    c = stC[gid]; v = stV[gid]; u = stU[gid];
    s = (v > 0.5f) ? 1.0f : 0.0f;              // bitwise-identical recompute
    acc = accB ? accB[gid] : 0.f;
  }
  size_t strideT = (size_t)B_ * (size_t)ncol;
#pragma unroll
  for (int tt = 0; tt < TC; ++tt) {
    float z = 0.f;
#pragma unroll
    for (int p = 0; p < NP; ++p)
      z = fencef(z + ZP[(size_t)p * pstride + (size_t)tt * strideT + gid]);
    float t1 = fencef(c * 0.5f);
    float t2 = fencef(t1 + z);
    c = fencef(t2 + bn);                       // ((c*0.5)+z)+b — np order
    float w1 = fencef(1.0f - s);
    float w2 = fencef(v * w1);
    float w3 = fencef(0.021f * s);
    float vv = fencef(w2 + w3);                // post-reset v'
    float w4 = fencef(s * 0.132f);
    float uu = fencef(u + w4);                 // post-reset u'
    float q1 = fencef(vv * vv);
    float q2 = fencef(q1 - vv);
    float q3 = fencef(q2 - uu);
    float dv = fencef(q3 + c);
    float r1 = fencef(-0.172f * vv);
    float r2 = fencef(0.529f * uu);
    float du = fencef(r1 + r2);
    v = fencef(vv + dv);
    u = fencef(uu + du);
    s = (v > 0.5f) ? 1.0f : 0.0f;
    if (Sout) Sout[(size_t)tt * strideT + gid] = s;
    acc = fencef(acc + s);                     // exact small integer
  }
  stC[gid] = c; stV[gid] = v; stU[gid] = u;
  if (accB) accB[gid] = acc;
  if (Out && last) Out[gid] = acc * 0.0625f;   // acc/16 exact
}

extern "C" void kernel_launch(void* const* d_in, const int* in_sizes, int n_in,
                              void* d_out, int out_size, void* d_ws, size_t ws_size,
                              hipStream_t stream) {
  const float* X  = (const float*)d_in[0];
  const float* W0 = (const float*)d_in[1];
  const float* b0 = (const float*)d_in[2];
  const float* W1 = (const float*)d_in[3];
  const float* b1 = (const float*)d_in[4];
  const float* W2 = (const float*)d_in[5];
  const float* b2 = (const float*)d_in[6];
  float* Out = (float*)d_out;
  char* ws = (char*)d_ws;
  constexpr size_t MB = 1024ull * 1024ull;
  // workspace layout — peak 96 MB (110 MB proven in-bounds since round 4)
  float* Xt   = (float*)(ws);              // [2048][2048] f32 = 16 MB
  float* ZP   = (float*)(ws + 16 * MB);    // 4 panels x [2048][1024] f32 = 32 MB
  float* S0c  = (float*)(ws + 48 * MB);    // [2048][1024] f32 =  8 MB
  float* S1c  = (float*)(ws + 56 * MB);    // [2048][1024] f32 =  8 MB
  float* st0c = (float*)(ws + 64 * MB);    // [1024*1024] f32 = 4 MB each
  float* st0v = (float*)(ws + 68 * MB);
  float* st0u = (float*)(ws + 72 * MB);
  float* st1c = (float*)(ws + 76 * MB);
  float* st1v = (float*)(ws + 80 * MB);
  float* st1u = (float*)(ws + 84 * MB);
  float* st2c = (float*)(ws + 88 * MB);    // [1024*512] f32 = 2 MB each
  float* st2v = (float*)(ws + 90 * MB);
  float* st2u = (float*)(ws + 92 * MB);
  float* accB = (float*)(ws + 94 * MB);    // [1024*512] f32 = 2 MB

  const size_t psH = (size_t)(TC * B_) * H0_;  // panel stride, N=1024 layers
  const size_t psO = (size_t)(TC * B_) * OUT_; // panel stride, N=512 layer

  for (int ci = 0; ci < NCHUNK; ++ci) {
    int first = (ci == 0) ? 1 : 0;
    int last = (ci == NCHUNK - 1) ? 1 : 0;
    transpose_x2<<<(B_ * IN_) / 256, 256, 0, stream>>>(X, Xt, ci * TC);
    // layer 0: K=2048 -> 4 panels; grid = 4 * 16 * 16 = 1024 blocks
    gemm_panel<<<4 * (TC * B_ / 128) * (H0_ / 64), 128, 0, stream>>>(
        Xt, W0, ZP, psH, H0_ / 64, IN_, H0_);
    lif_chunk<4><<<(B_ * H0_) / 256, 256, 0, stream>>>(
        ZP, psH, b0, st0c, st0v, st0u, S0c, nullptr, nullptr, H0_, first, 0);
    // layer 1: K=1024 -> 2 panels; grid = 2 * 16 * 16 = 512 blocks
    gemm_panel<<<2 * (TC * B_ / 128) * (H1_ / 64), 128, 0, stream>>>(
        S0c, W1, ZP, psH, H1_ / 64, H0_, H1_);
    lif_chunk<2><<<(B_ * H1_) / 256, 256, 0, stream>>>(
        ZP, psH, b1, st1c, st1v, st1u, S1c, nullptr, nullptr, H1_, first, 0);
    // layer 2: K=1024 -> 2 panels; grid = 2 * 16 * 8 = 256 blocks
    gemm_panel<<<2 * (TC * B_ / 128) * (OUT_ / 64), 128, 0, stream>>>(
        S1c, W2, ZP, psO, OUT_ / 64, H1_, OUT_);
    lif_chunk<2><<<(B_ * OUT_) / 256, 256, 0, stream>>>(
        ZP, psO, b2, st2c, st2v, st2u, nullptr, accB, Out, OUT_, first, last);
  }
}

// Round 21
// 2056.975 us; speedup vs baseline: 1.1734x; 1.1734x over previous
//
#include <hip/hip_runtime.h>
#include <stdint.h>

#pragma clang fp contract(off)

constexpr int B_ = 1024, IN_ = 2048, H0_ = 1024, H1_ = 1024, OUT_ = 512;
constexpr int TC = 2;        // timesteps per chunk
constexpr int NCHUNK = 8;    // 16 / TC
constexpr int PQ = 512;      // K-panel width (bitwise-verified in round 16)

// Arithmetic fence: forces the f32 value to materialize — kills FMA contraction
// and reassociation across this point even under -ffp-contract=fast.
static __device__ __forceinline__ float fencef(float x) {
  asm volatile("" : "+v"(x));
  return x;
}

// ---------- transpose chunk: X[b][i][t0+tc] -> Xt[tc*B + b][i] (f32) ----------
__global__ void transpose_x2(const float* __restrict__ X, float* __restrict__ Xt, int t0) {
  int idx = blockIdx.x * 256 + threadIdx.x;  // b*IN + i
  int b = idx >> 11, i = idx & (IN_ - 1);
  float2 v = *(const float2*)(X + (size_t)idx * 16 + t0);
  Xt[(size_t)b * IN_ + i] = v.x;
  Xt[(size_t)(B_ + b) * IN_ + i] = v.y;
}

// ---------- f32 NT GEMM, ONE 512-panel per block, 64x64 tile ----------
// Panel p of C[M][N]: acc = sum_{k=512p..512p+511} fma(A[m,k], B[n,k], acc),
// single accumulator, ascending k, f32 FMA — bitwise-identical chain to the
// round-16/17 passing kernels. Occupancy-focused shape: 64x64 tile, 17.4 KB
// LDS -> 8 blocks/CU co-resident (r17-r20 showed 4-block configs stall ~45%
// issue-idle at the staging barriers regardless of LDS traffic or prefetch).
// BM=64, BN=64, BK=32; 256 threads; 4x4 micro-tile.
__global__ __launch_bounds__(256) void gemm_panel(
    const float* __restrict__ A, const float* __restrict__ Bw,
    float* __restrict__ ZP, size_t pstride, int Ntiles, int K, int N) {
  __shared__ float As[32][68];  // k-major, padded (row stride 272 B, 16B-aligned)
  __shared__ float Bs[32][68];

  // bijective XCD swizzle (all grids here are multiples of 8)
  int bid = blockIdx.x, cpx = gridDim.x >> 3;
  int wg = (bid & 7) * cpx + (bid >> 3);
  int tpp = (gridDim.x / ((K + PQ - 1) / PQ));     // tiles per panel = Mt*Nt
  int p = wg / tpp, r = wg - p * tpp;
  int bm = r / Ntiles, bn = r - bm * Ntiles;

  int tid = threadIdx.x;
  int ra = tid >> 2, ca = (tid & 3) * 8;   // staging: row 0..63, 8-col slice
  int tx = tid & 15, ty = tid >> 4;        // micro-tile: cols tx*4.., rows ty*4..

  float acc[4][4] = {};   // THE panel chain accumulators (init 0, ascending k)
  const size_t rowA = (size_t)(bm * 64 + ra) * K + p * PQ;
  const size_t rowB = (size_t)(bn * 64 + ra) * K + p * PQ;

  for (int kk = 0; kk < PQ; kk += 32) {
    float4 a0 = *(const float4*)(A + rowA + kk + ca);
    float4 a1 = *(const float4*)(A + rowA + kk + ca + 4);
    float4 b0 = *(const float4*)(Bw + rowB + kk + ca);
    float4 b1 = *(const float4*)(Bw + rowB + kk + ca + 4);
    __syncthreads();  // previous-tile reads done before overwrite
    As[ca + 0][ra] = a0.x; As[ca + 1][ra] = a0.y;
    As[ca + 2][ra] = a0.z; As[ca + 3][ra] = a0.w;
    As[ca + 4][ra] = a1.x; As[ca + 5][ra] = a1.y;
    As[ca + 6][ra] = a1.z; As[ca + 7][ra] = a1.w;
    Bs[ca + 0][ra] = b0.x; Bs[ca + 1][ra] = b0.y;
    Bs[ca + 2][ra] = b0.z; Bs[ca + 3][ra] = b0.w;
    Bs[ca + 4][ra] = b1.x; Bs[ca + 5][ra] = b1.y;
    Bs[ca + 6][ra] = b1.z; Bs[ca + 7][ra] = b1.w;
    __syncthreads();  // tile ready
#pragma unroll
    for (int k = 0; k < 32; ++k) {   // ascending k — order is frozen
      float ar[4], br[4];
#pragma unroll
      for (int i = 0; i < 4; ++i) ar[i] = As[k][ty * 4 + i];
#pragma unroll
      for (int j = 0; j < 4; ++j) br[j] = Bs[k][tx * 4 + j];
#pragma unroll
      for (int i = 0; i < 4; ++i)
#pragma unroll
        for (int j = 0; j < 4; ++j)
          acc[i][j] = __builtin_fmaf(ar[i], br[j], acc[i][j]);
    }
  }
  float* Cb = ZP + p * pstride + (size_t)(bm * 64 + ty * 4) * N + bn * 64 + tx * 4;
#pragma unroll
  for (int i = 0; i < 4; ++i)
#pragma unroll
    for (int j = 0; j < 4; ++j)
      Cb[(size_t)i * N + j] = acc[i][j];
}

// ---------- FLOAT32 LIF over TC steps + in-order panel combine, fenced ----------
// z = (((0 + P0) + P1) + ...) — bitwise-identical to round 16's creg loop.
template <int NP>
__global__ void lif_chunk(const float* __restrict__ ZP, size_t pstride,
                          const float* __restrict__ bias,
                          float* __restrict__ stC, float* __restrict__ stV,
                          float* __restrict__ stU, float* __restrict__ Sout,
                          float* __restrict__ accB, float* __restrict__ Out,
                          int ncol, int first, int last) {
  int gid = blockIdx.x * 256 + threadIdx.x;  // b*ncol + n
  int n = gid & (ncol - 1);
  float bn = bias[n];
  float c, v, u, s, acc;
  if (first) {
    c = 0.f; v = 0.f; u = 0.f; s = 0.f; acc = 0.f;
  } else {
    c = stC[gid]; v = stV[gid]; u = stU[gid];
    s = (v > 0.5f) ? 1.0f : 0.0f;              // bitwise-identical recompute
    acc = accB ? accB[gid] : 0.f;
  }
  size_t strideT = (size_t)B_ * (size_t)ncol;
#pragma unroll
  for (int tt = 0; tt < TC; ++tt) {
    float z = 0.f;
#pragma unroll
    for (int p = 0; p < NP; ++p)
      z = fencef(z + ZP[(size_t)p * pstride + (size_t)tt * strideT + gid]);
    float t1 = fencef(c * 0.5f);
    float t2 = fencef(t1 + z);
    c = fencef(t2 + bn);                       // ((c*0.5)+z)+b — np order
    float w1 = fencef(1.0f - s);
    float w2 = fencef(v * w1);
    float w3 = fencef(0.021f * s);
    float vv = fencef(w2 + w3);                // post-reset v'
    float w4 = fencef(s * 0.132f);
    float uu = fencef(u + w4);                 // post-reset u'
    float q1 = fencef(vv * vv);
    float q2 = fencef(q1 - vv);
    float q3 = fencef(q2 - uu);
    float dv = fencef(q3 + c);
    float r1 = fencef(-0.172f * vv);
    float r2 = fencef(0.529f * uu);
    float du = fencef(r1 + r2);
    v = fencef(vv + dv);
    u = fencef(uu + du);
    s = (v > 0.5f) ? 1.0f : 0.0f;
    if (Sout) Sout[(size_t)tt * strideT + gid] = s;
    acc = fencef(acc + s);                     // exact small integer
  }
  stC[gid] = c; stV[gid] = v; stU[gid] = u;
  if (accB) accB[gid] = acc;
  if (Out && last) Out[gid] = acc * 0.0625f;   // acc/16 exact
}

extern "C" void kernel_launch(void* const* d_in, const int* in_sizes, int n_in,
                              void* d_out, int out_size, void* d_ws, size_t ws_size,
                              hipStream_t stream) {
  const float* X  = (const float*)d_in[0];
  const float* W0 = (const float*)d_in[1];
  const float* b0 = (const float*)d_in[2];
  const float* W1 = (const float*)d_in[3];
  const float* b1 = (const float*)d_in[4];
  const float* W2 = (const float*)d_in[5];
  const float* b2 = (const float*)d_in[6];
  float* Out = (float*)d_out;
  char* ws = (char*)d_ws;
  constexpr size_t MB = 1024ull * 1024ull;
  // workspace layout — peak 96 MB (110 MB proven in-bounds since round 4)
  float* Xt   = (float*)(ws);              // [2048][2048] f32 = 16 MB
  float* ZP   = (float*)(ws + 16 * MB);    // 4 panels x [2048][1024] f32 = 32 MB
  float* S0c  = (float*)(ws + 48 * MB);    // [2048][1024] f32 =  8 MB
  float* S1c  = (float*)(ws + 56 * MB);    // [2048][1024] f32 =  8 MB
  float* st0c = (float*)(ws + 64 * MB);    // [1024*1024] f32 = 4 MB each
  float* st0v = (float*)(ws + 68 * MB);
  float* st0u = (float*)(ws + 72 * MB);
  float* st1c = (float*)(ws + 76 * MB);
  float* st1v = (float*)(ws + 80 * MB);
  float* st1u = (float*)(ws + 84 * MB);
  float* st2c = (float*)(ws + 88 * MB);    // [1024*512] f32 = 2 MB each
  float* st2v = (float*)(ws + 90 * MB);
  float* st2u = (float*)(ws + 92 * MB);
  float* accB = (float*)(ws + 94 * MB);    // [1024*512] f32 = 2 MB

  const size_t psH = (size_t)(TC * B_) * H0_;  // panel stride, N=1024 layers
  const size_t psO = (size_t)(TC * B_) * OUT_; // panel stride, N=512 layer

  for (int ci = 0; ci < NCHUNK; ++ci) {
    int first = (ci == 0) ? 1 : 0;
    int last = (ci == NCHUNK - 1) ? 1 : 0;
    transpose_x2<<<(B_ * IN_) / 256, 256, 0, stream>>>(X, Xt, ci * TC);
    // layer 0: K=2048 -> 4 panels; grid = 4 * 32 * 16 = 2048 blocks (8/CU)
    gemm_panel<<<4 * (TC * B_ / 64) * (H0_ / 64), 256, 0, stream>>>(
        Xt, W0, ZP, psH, H0_ / 64, IN_, H0_);
    lif_chunk<4><<<(B_ * H0_) / 256, 256, 0, stream>>>(
        ZP, psH, b0, st0c, st0v, st0u, S0c, nullptr, nullptr, H0_, first, 0);
    // layer 1: K=1024 -> 2 panels; grid = 2 * 32 * 16 = 1024 blocks (4/CU)
    gemm_panel<<<2 * (TC * B_ / 64) * (H1_ / 64), 256, 0, stream>>>(
        S0c, W1, ZP, psH, H1_ / 64, H0_, H1_);
    lif_chunk<2><<<(B_ * H1_) / 256, 256, 0, stream>>>(
        ZP, psH, b1, st1c, st1v, st1u, S1c, nullptr, nullptr, H1_, first, 0);
    // layer 2: K=1024 -> 2 panels; grid = 2 * 32 * 8 = 512 blocks (2/CU)
    gemm_panel<<<2 * (TC * B_ / 64) * (OUT_ / 64), 256, 0, stream>>>(
        S1c, W2, ZP, psO, OUT_ / 64, H1_, OUT_);
    lif_chunk<2><<<(B_ * OUT_) / 256, 256, 0, stream>>>(
        ZP, psO, b2, st2c, st2v, st2u, nullptr, accB, Out, OUT_, first, last);
  }
}

// Round 22
// 1970.924 us; speedup vs baseline: 1.2247x; 1.0437x over previous
//
#include <hip/hip_runtime.h>
#include <stdint.h>

#pragma clang fp contract(off)

constexpr int B_ = 1024, IN_ = 2048, H0_ = 1024, H1_ = 1024, OUT_ = 512;
constexpr int TC = 2;        // timesteps per chunk
constexpr int NCHUNK = 8;    // 16 / TC
constexpr int PQ = 512;      // K-panel width (bitwise-verified in round 16)

// Arithmetic fence: forces the f32 value to materialize — kills FMA contraction
// and reassociation across this point even under -ffp-contract=fast.
static __device__ __forceinline__ float fencef(float x) {
  asm volatile("" : "+v"(x));
  return x;
}

// ---------- transpose chunk: X[b][i][t0+tc] -> Xt[tc*B + b][i] (f32) ----------
__global__ void transpose_x2(const float* __restrict__ X, float* __restrict__ Xt, int t0) {
  int idx = blockIdx.x * 256 + threadIdx.x;  // b*IN + i
  int b = idx >> 11, i = idx & (IN_ - 1);
  float2 v = *(const float2*)(X + (size_t)idx * 16 + t0);
  Xt[(size_t)b * IN_ + i] = v.x;
  Xt[(size_t)(B_ + b) * IN_ + i] = v.y;
}

// ---------- f32 NT GEMM, ONE 512-panel per block, fragment-pipelined ----------
// Panel p of C[M][N]: acc = sum_{k=512p..512p+511} fma(A[m,k], B[n,k], acc),
// single accumulator, ascending k, f32 FMA — bitwise-identical chain to the
// round-16/17 passing kernels. Inner loop explicitly double-buffers the LDS
// fragments (load k+1's ar/br into the alternate register set before k's FMAs)
// — r17-r21 showed the stall is the per-k ds_read->FMA lgkmcnt wait, which the
// compiler (at 68 VGPRs) never pipelined. FMA order per element unchanged.
// BM=128, BN=64, BK=32; 256 threads; 8x4 micro-tile.
__global__ __launch_bounds__(256) void gemm_panel(
    const float* __restrict__ A, const float* __restrict__ Bw,
    float* __restrict__ ZP, size_t pstride, int Ntiles, int K, int N) {
  __shared__ float As[32][132];  // k-major, padded
  __shared__ float Bs[32][68];

  // bijective XCD swizzle (all grids here are multiples of 8)
  int bid = blockIdx.x, cpx = gridDim.x >> 3;
  int wg = (bid & 7) * cpx + (bid >> 3);
  int tpp = (gridDim.x / ((K + PQ - 1) / PQ));     // tiles per panel = Mt*Nt
  int p = wg / tpp, r = wg - p * tpp;
  int bm = r / Ntiles, bn = r - bm * Ntiles;

  int tid = threadIdx.x;
  int ra = tid >> 1, ca = (tid & 1) * 16;  // A staging: row 0..127, 16-col half
  int rb = tid >> 2, cb = (tid & 3) * 8;   // B staging: row 0..63, 8-col quarter
  int tx = tid & 15, ty = tid >> 4;        // micro-tile: cols tx*4.., rows ty*8..

  float acc[8][4] = {};   // THE panel chain accumulators (init 0, ascending k)
  const size_t rowA = (size_t)(bm * 128 + ra) * K + p * PQ;
  const size_t rowB = (size_t)(bn * 64 + rb) * K + p * PQ;

#define FRAG_LOAD(AR, BR, kk)                                      \
  do {                                                             \
    _Pragma("unroll")                                              \
    for (int i = 0; i < 8; ++i) AR[i] = As[kk][ty * 8 + i];        \
    _Pragma("unroll")                                              \
    for (int j = 0; j < 4; ++j) BR[j] = Bs[kk][tx * 4 + j];        \
  } while (0)

#define FRAG_FMA(AR, BR)                                           \
  do {                                                             \
    _Pragma("unroll")                                              \
    for (int i = 0; i < 8; ++i)                                    \
      _Pragma("unroll")                                            \
      for (int j = 0; j < 4; ++j)                                  \
        acc[i][j] = __builtin_fmaf(AR[i], BR[j], acc[i][j]);       \
  } while (0)

  for (int kk = 0; kk < PQ; kk += 32) {
    float4 a0 = *(const float4*)(A + rowA + kk + ca);
    float4 a1 = *(const float4*)(A + rowA + kk + ca + 4);
    float4 a2 = *(const float4*)(A + rowA + kk + ca + 8);
    float4 a3 = *(const float4*)(A + rowA + kk + ca + 12);
    float4 b0 = *(const float4*)(Bw + rowB + kk + cb);
    float4 b1 = *(const float4*)(Bw + rowB + kk + cb + 4);
    __syncthreads();  // previous-tile reads done before overwrite
    As[ca + 0][ra] = a0.x;  As[ca + 1][ra] = a0.y;
    As[ca + 2][ra] = a0.z;  As[ca + 3][ra] = a0.w;
    As[ca + 4][ra] = a1.x;  As[ca + 5][ra] = a1.y;
    As[ca + 6][ra] = a1.z;  As[ca + 7][ra] = a1.w;
    As[ca + 8][ra] = a2.x;  As[ca + 9][ra] = a2.y;
    As[ca + 10][ra] = a2.z; As[ca + 11][ra] = a2.w;
    As[ca + 12][ra] = a3.x; As[ca + 13][ra] = a3.y;
    As[ca + 14][ra] = a3.z; As[ca + 15][ra] = a3.w;
    Bs[cb + 0][rb] = b0.x;  Bs[cb + 1][rb] = b0.y;
    Bs[cb + 2][rb] = b0.z;  Bs[cb + 3][rb] = b0.w;
    Bs[cb + 4][rb] = b1.x;  Bs[cb + 5][rb] = b1.y;
    Bs[cb + 6][rb] = b1.z;  Bs[cb + 7][rb] = b1.w;
    __syncthreads();  // tile ready

    // fragment-pipelined inner loop: 2 register sets, alternate per k.
    float arA[8], brA[4], arB[8], brB[4];
    FRAG_LOAD(arA, brA, 0);
#pragma unroll
    for (int k = 0; k < 32; k += 2) {     // fully unrolled; sets static
      if (k + 1 < 32) FRAG_LOAD(arB, brB, k + 1);  // prefetch k+1
      FRAG_FMA(arA, brA);                           // compute k (ascending)
      if (k + 2 < 32) FRAG_LOAD(arA, brA, k + 2);  // prefetch k+2
      if (k + 1 < 32) FRAG_FMA(arB, brB);          // compute k+1
    }
  }
#undef FRAG_LOAD
#undef FRAG_FMA

  float* Cb = ZP + p * pstride + (size_t)(bm * 128 + ty * 8) * N + bn * 64 + tx * 4;
#pragma unroll
  for (int i = 0; i < 8; ++i)
#pragma unroll
    for (int j = 0; j < 4; ++j)
      Cb[(size_t)i * N + j] = acc[i][j];
}

// ---------- FLOAT32 LIF over TC steps + in-order panel combine, fenced ----------
// z = (((0 + P0) + P1) + ...) — bitwise-identical to round 16's creg loop.
template <int NP>
__global__ void lif_chunk(const float* __restrict__ ZP, size_t pstride,
                          const float* __restrict__ bias,
                          float* __restrict__ stC, float* __restrict__ stV,
                          float* __restrict__ stU, float* __restrict__ Sout,
                          float* __restrict__ accB, float* __restrict__ Out,
                          int ncol, int first, int last) {
  int gid = blockIdx.x * 256 + threadIdx.x;  // b*ncol + n
  int n = gid & (ncol - 1);
  float bn = bias[n];
  float c, v, u, s, acc;
  if (first) {
    c = 0.f; v = 0.f; u = 0.f; s = 0.f; acc = 0.f;
  } else {
    c = stC[gid]; v = stV[gid]; u = stU[gid];
    s = (v > 0.5f) ? 1.0f : 0.0f;              // bitwise-identical recompute
    acc = accB ? accB[gid] : 0.f;
  }
  size_t strideT = (size_t)B_ * (size_t)ncol;
#pragma unroll
  for (int tt = 0; tt < TC; ++tt) {
    float z = 0.f;
#pragma unroll
    for (int p = 0; p < NP; ++p)
      z = fencef(z + ZP[(size_t)p * pstride + (size_t)tt * strideT + gid]);
    float t1 = fencef(c * 0.5f);
    float t2 = fencef(t1 + z);
    c = fencef(t2 + bn);                       // ((c*0.5)+z)+b — np order
    float w1 = fencef(1.0f - s);
    float w2 = fencef(v * w1);
    float w3 = fencef(0.021f * s);
    float vv = fencef(w2 + w3);                // post-reset v'
    float w4 = fencef(s * 0.132f);
    float uu = fencef(u + w4);                 // post-reset u'
    float q1 = fencef(vv * vv);
    float q2 = fencef(q1 - vv);
    float q3 = fencef(q2 - uu);
    float dv = fencef(q3 + c);
    float r1 = fencef(-0.172f * vv);
    float r2 = fencef(0.529f * uu);
    float du = fencef(r1 + r2);
    v = fencef(vv + dv);
    u = fencef(uu + du);
    s = (v > 0.5f) ? 1.0f : 0.0f;
    if (Sout) Sout[(size_t)tt * strideT + gid] = s;
    acc = fencef(acc + s);                     // exact small integer
  }
  stC[gid] = c; stV[gid] = v; stU[gid] = u;
  if (accB) accB[gid] = acc;
  if (Out && last) Out[gid] = acc * 0.0625f;   // acc/16 exact
}

extern "C" void kernel_launch(void* const* d_in, const int* in_sizes, int n_in,
                              void* d_out, int out_size, void* d_ws, size_t ws_size,
                              hipStream_t stream) {
  const float* X  = (const float*)d_in[0];
  const float* W0 = (const float*)d_in[1];
  const float* b0 = (const float*)d_in[2];
  const float* W1 = (const float*)d_in[3];
  const float* b1 = (const float*)d_in[4];
  const float* W2 = (const float*)d_in[5];
  const float* b2 = (const float*)d_in[6];
  float* Out = (float*)d_out;
  char* ws = (char*)d_ws;
  constexpr size_t MB = 1024ull * 1024ull;
  // workspace layout — peak 96 MB (110 MB proven in-bounds since round 4)
  float* Xt   = (float*)(ws);              // [2048][2048] f32 = 16 MB
  float* ZP   = (float*)(ws + 16 * MB);    // 4 panels x [2048][1024] f32 = 32 MB
  float* S0c  = (float*)(ws + 48 * MB);    // [2048][1024] f32 =  8 MB
  float* S1c  = (float*)(ws + 56 * MB);    // [2048][1024] f32 =  8 MB
  float* st0c = (float*)(ws + 64 * MB);    // [1024*1024] f32 = 4 MB each
  float* st0v = (float*)(ws + 68 * MB);
  float* st0u = (float*)(ws + 72 * MB);
  float* st1c = (float*)(ws + 76 * MB);
  float* st1v = (float*)(ws + 80 * MB);
  float* st1u = (float*)(ws + 84 * MB);
  float* st2c = (float*)(ws + 88 * MB);    // [1024*512] f32 = 2 MB each
  float* st2v = (float*)(ws + 90 * MB);
  float* st2u = (float*)(ws + 92 * MB);
  float* accB = (float*)(ws + 94 * MB);    // [1024*512] f32 = 2 MB

  const size_t psH = (size_t)(TC * B_) * H0_;  // panel stride, N=1024 layers
  const size_t psO = (size_t)(TC * B_) * OUT_; // panel stride, N=512 layer

  for (int ci = 0; ci < NCHUNK; ++ci) {
    int first = (ci == 0) ? 1 : 0;
    int last = (ci == NCHUNK - 1) ? 1 : 0;
    transpose_x2<<<(B_ * IN_) / 256, 256, 0, stream>>>(X, Xt, ci * TC);
    // layer 0: K=2048 -> 4 panels; grid = 4 * 16 * 16 = 1024 blocks
    gemm_panel<<<4 * (TC * B_ / 128) * (H0_ / 64), 256, 0, stream>>>(
        Xt, W0, ZP, psH, H0_ / 64, IN_, H0_);
    lif_chunk<4><<<(B_ * H0_) / 256, 256, 0, stream>>>(
        ZP, psH, b0, st0c, st0v, st0u, S0c, nullptr, nullptr, H0_, first, 0);
    // layer 1: K=1024 -> 2 panels; grid = 2 * 16 * 16 = 512 blocks
    gemm_panel<<<2 * (TC * B_ / 128) * (H1_ / 64), 256, 0, stream>>>(
        S0c, W1, ZP, psH, H1_ / 64, H0_, H1_);
    lif_chunk<2><<<(B_ * H1_) / 256, 256, 0, stream>>>(
        ZP, psH, b1, st1c, st1v, st1u, S1c, nullptr, nullptr, H1_, first, 0);
    // layer 2: K=1024 -> 2 panels; grid = 2 * 16 * 8 = 256 blocks
    gemm_panel<<<2 * (TC * B_ / 128) * (OUT_ / 64), 256, 0, stream>>>(
        S1c, W2, ZP, psO, OUT_ / 64, H1_, OUT_);
    lif_chunk<2><<<(B_ * OUT_) / 256, 256, 0, stream>>>(
        ZP, psO, b2, st2c, st2v, st2u, nullptr, accB, Out, OUT_, first, last);
  }
}

// Round 23
// 1916.314 us; speedup vs baseline: 1.2596x; 1.0285x over previous
//
#include <hip/hip_runtime.h>
#include <stdint.h>

#pragma clang fp contract(off)

constexpr int B_ = 1024, IN_ = 2048, H0_ = 1024, H1_ = 1024, OUT_ = 512;
constexpr int TC = 4;        // timesteps per chunk (raised for GEMM grid depth)
constexpr int NCHUNK = 4;    // 16 / TC
constexpr int PQ = 512;      // K-panel width (bitwise-verified in round 16)

// Arithmetic fence: forces the f32 value to materialize — kills FMA contraction
// and reassociation across this point even under -ffp-contract=fast.
static __device__ __forceinline__ float fencef(float x) {
  asm volatile("" : "+v"(x));
  return x;
}

// ---------- transpose chunk: X[b][i][t0..t0+3] -> Xt[tt*B + b][i] (f32) ----------
__global__ void transpose_x4(const float* __restrict__ X, float* __restrict__ Xt, int t0) {
  int idx = blockIdx.x * 256 + threadIdx.x;  // b*IN + i
  int b = idx >> 11, i = idx & (IN_ - 1);
  float4 v = *(const float4*)(X + (size_t)idx * 16 + t0);  // 4 consecutive t's
  Xt[(size_t)b * IN_ + i] = v.x;
  Xt[(size_t)(B_ + b) * IN_ + i] = v.y;
  Xt[(size_t)(2 * B_ + b) * IN_ + i] = v.z;
  Xt[(size_t)(3 * B_ + b) * IN_ + i] = v.w;
}

// ---------- f32 NT GEMM, ONE 512-panel per block, 8x8 micro (r20 kernel) ----------
// Panel p of C[M][N]: acc = sum_{k=512p..512p+511} fma(A[m,k], B[n,k], acc),
// single accumulator, ascending k, f32 FMA — bitwise-identical chain to the
// round-16..22 passing kernels. r20 proved this kernel bitwise; its LDS:FMA
// pipe ratio (4 ds_read_b128 per 64 FMA = 1.5x) is the best achieved — it only
// lost because the TC=2 grid capped it at ~1.4 waves/SIMD. TC=4 doubles the
// grid: 2048 blocks -> 6 blocks/CU (LDS-capped) = 3 waves/SIMD.
// BM=128, BN=64, BK=32; 128 threads (2 waves); 8x8 micro-tile.
__global__ __launch_bounds__(128) void gemm_panel(
    const float* __restrict__ A, const float* __restrict__ Bw,
    float* __restrict__ ZP, size_t pstride, int Ntiles, int K, int N) {
  __shared__ float As[32][132];  // k-major, padded
  __shared__ float Bs[32][68];

  // bijective XCD swizzle (all grids here are multiples of 8)
  int bid = blockIdx.x, cpx = gridDim.x >> 3;
  int wg = (bid & 7) * cpx + (bid >> 3);
  int tpp = (gridDim.x / ((K + PQ - 1) / PQ));     // tiles per panel = Mt*Nt
  int p = wg / tpp, r = wg - p * tpp;
  int bm = r / Ntiles, bn = r - bm * Ntiles;

  int tid = threadIdx.x;
  int tx = tid & 7, ty = tid >> 3;         // micro-tile: cols tx*8.., rows ty*8..
  int rb = tid >> 1, cb = (tid & 1) * 16;  // B staging: row 0..63, 16-col half

  float acc[8][8] = {};   // THE panel chain accumulators (init 0, ascending k)
  const size_t rowA = (size_t)(bm * 128 + tid) * K + p * PQ;  // A staging: 1 row/thread
  const size_t rowB = (size_t)(bn * 64 + rb) * K + p * PQ;

  for (int kk = 0; kk < PQ; kk += 32) {
    float4 av[8], bv[4];
#pragma unroll
    for (int q = 0; q < 8; ++q)
      av[q] = *(const float4*)(A + rowA + kk + q * 4);
#pragma unroll
    for (int q = 0; q < 4; ++q)
      bv[q] = *(const float4*)(Bw + rowB + kk + cb + q * 4);
    __syncthreads();  // previous-tile reads done before overwrite
#pragma unroll
    for (int q = 0; q < 8; ++q) {
      As[q * 4 + 0][tid] = av[q].x;
      As[q * 4 + 1][tid] = av[q].y;
      As[q * 4 + 2][tid] = av[q].z;
      As[q * 4 + 3][tid] = av[q].w;
    }
#pragma unroll
    for (int q = 0; q < 4; ++q) {
      Bs[cb + q * 4 + 0][rb] = bv[q].x;
      Bs[cb + q * 4 + 1][rb] = bv[q].y;
      Bs[cb + q * 4 + 2][rb] = bv[q].z;
      Bs[cb + q * 4 + 3][rb] = bv[q].w;
    }
    __syncthreads();  // tile ready
#pragma unroll
    for (int k = 0; k < 32; ++k) {   // ascending k — order is frozen
      float ar[8], br[8];
#pragma unroll
      for (int i = 0; i < 8; ++i) ar[i] = As[k][ty * 8 + i];
#pragma unroll
      for (int j = 0; j < 8; ++j) br[j] = Bs[k][tx * 8 + j];
#pragma unroll
      for (int i = 0; i < 8; ++i)
#pragma unroll
        for (int j = 0; j < 8; ++j)
          acc[i][j] = __builtin_fmaf(ar[i], br[j], acc[i][j]);
    }
  }
  float* Cb = ZP + p * pstride + (size_t)(bm * 128 + ty * 8) * N + bn * 64 + tx * 8;
#pragma unroll
  for (int i = 0; i < 8; ++i)
#pragma unroll
    for (int j = 0; j < 8; ++j)
      Cb[(size_t)i * N + j] = acc[i][j];
}

// ---------- FLOAT32 LIF over TC steps + in-order panel combine, fenced ----------
// z = (((0 + P0) + P1) + ...) — bitwise-identical to round 16's creg loop.
template <int NP>
__global__ void lif_chunk(const float* __restrict__ ZP, size_t pstride,
                          const float* __restrict__ bias,
                          float* __restrict__ stC, float* __restrict__ stV,
                          float* __restrict__ stU, float* __restrict__ Sout,
                          float* __restrict__ accB, float* __restrict__ Out,
                          int ncol, int first, int last) {
  int gid = blockIdx.x * 256 + threadIdx.x;  // b*ncol + n
  int n = gid & (ncol - 1);
  float bn = bias[n];
  float c, v, u, s, acc;
  if (first) {
    c = 0.f; v = 0.f; u = 0.f; s = 0.f; acc = 0.f;
  } else {
    c = stC[gid]; v = stV[gid]; u = stU[gid];
    s = (v > 0.5f) ? 1.0f : 0.0f;              // bitwise-identical recompute
    acc = accB ? accB[gid] : 0.f;
  }
  size_t strideT = (size_t)B_ * (size_t)ncol;
#pragma unroll
  for (int tt = 0; tt < TC; ++tt) {
    float z = 0.f;
#pragma unroll
    for (int p = 0; p < NP; ++p)
      z = fencef(z + ZP[(size_t)p * pstride + (size_t)tt * strideT + gid]);
    float t1 = fencef(c * 0.5f);
    float t2 = fencef(t1 + z);
    c = fencef(t2 + bn);                       // ((c*0.5)+z)+b — np order
    float w1 = fencef(1.0f - s);
    float w2 = fencef(v * w1);
    float w3 = fencef(0.021f * s);
    float vv = fencef(w2 + w3);                // post-reset v'
    float w4 = fencef(s * 0.132f);
    float uu = fencef(u + w4);                 // post-reset u'
    float q1 = fencef(vv * vv);
    float q2 = fencef(q1 - vv);
    float q3 = fencef(q2 - uu);
    float dv = fencef(q3 + c);
    float r1 = fencef(-0.172f * vv);
    float r2 = fencef(0.529f * uu);
    float du = fencef(r1 + r2);
    v = fencef(vv + dv);
    u = fencef(uu + du);
    s = (v > 0.5f) ? 1.0f : 0.0f;
    if (Sout) Sout[(size_t)tt * strideT + gid] = s;
    acc = fencef(acc + s);                     // exact small integer
  }
  stC[gid] = c; stV[gid] = v; stU[gid] = u;
  if (accB) accB[gid] = acc;
  if (Out && last) Out[gid] = acc * 0.0625f;   // acc/16 exact
}

extern "C" void kernel_launch(void* const* d_in, const int* in_sizes, int n_in,
                              void* d_out, int out_size, void* d_ws, size_t ws_size,
                              hipStream_t stream) {
  const float* X  = (const float*)d_in[0];
  const float* W0 = (const float*)d_in[1];
  const float* b0 = (const float*)d_in[2];
  const float* W1 = (const float*)d_in[3];
  const float* b1 = (const float*)d_in[4];
  const float* W2 = (const float*)d_in[5];
  const float* b2 = (const float*)d_in[6];
  float* Out = (float*)d_out;
  char* ws = (char*)d_ws;
  constexpr size_t MB = 1024ull * 1024ull;
  // workspace layout — peak 160 MB
  float* Xt   = (float*)(ws);               // [4096][2048] f32 = 32 MB
  float* ZP   = (float*)(ws + 32 * MB);     // 4 panels x [4096][1024] f32 = 64 MB
  float* S0c  = (float*)(ws + 96 * MB);     // [4096][1024] f32 = 16 MB
  float* S1c  = (float*)(ws + 112 * MB);    // [4096][1024] f32 = 16 MB
  float* st0c = (float*)(ws + 128 * MB);    // [1024*1024] f32 = 4 MB each
  float* st0v = (float*)(ws + 132 * MB);
  float* st0u = (float*)(ws + 136 * MB);
  float* st1c = (float*)(ws + 140 * MB);
  float* st1v = (float*)(ws + 144 * MB);
  float* st1u = (float*)(ws + 148 * MB);
  float* st2c = (float*)(ws + 152 * MB);    // [1024*512] f32 = 2 MB each
  float* st2v = (float*)(ws + 154 * MB);
  float* st2u = (float*)(ws + 156 * MB);
  float* accB = (float*)(ws + 158 * MB);    // [1024*512] f32 = 2 MB

  const size_t psH = (size_t)(TC * B_) * H0_;  // panel stride, N=1024 layers
  const size_t psO = (size_t)(TC * B_) * OUT_; // panel stride, N=512 layer

  for (int ci = 0; ci < NCHUNK; ++ci) {
    int first = (ci == 0) ? 1 : 0;
    int last = (ci == NCHUNK - 1) ? 1 : 0;
    transpose_x4<<<(B_ * IN_) / 256, 256, 0, stream>>>(X, Xt, ci * TC);
    // layer 0: K=2048 -> 4 panels; grid = 4 * 32 * 16 = 2048 blocks (6/CU, 3 w/SIMD)
    gemm_panel<<<4 * (TC * B_ / 128) * (H0_ / 64), 128, 0, stream>>>(
        Xt, W0, ZP, psH, H0_ / 64, IN_, H0_);
    lif_chunk<4><<<(B_ * H0_) / 256, 256, 0, stream>>>(
        ZP, psH, b0, st0c, st0v, st0u, S0c, nullptr, nullptr, H0_, first, 0);
    // layer 1: K=1024 -> 2 panels; grid = 2 * 32 * 16 = 1024 blocks
    gemm_panel<<<2 * (TC * B_ / 128) * (H1_ / 64), 128, 0, stream>>>(
        S0c, W1, ZP, psH, H1_ / 64, H0_, H1_);
    lif_chunk<2><<<(B_ * H1_) / 256, 256, 0, stream>>>(
        ZP, psH, b1, st1c, st1v, st1u, S1c, nullptr, nullptr, H1_, first, 0);
    // layer 2: K=1024 -> 2 panels; grid = 2 * 32 * 8 = 512 blocks
    gemm_panel<<<2 * (TC * B_ / 128) * (OUT_ / 64), 128, 0, stream>>>(
        S1c, W2, ZP, psO, OUT_ / 64, H1_, OUT_);
    lif_chunk<2><<<(B_ * OUT_) / 256, 256, 0, stream>>>(
        ZP, psO, b2, st2c, st2v, st2u, nullptr, accB, Out, OUT_, first, last);
  }
}

// Round 24
// 1772.606 us; speedup vs baseline: 1.3617x; 1.0811x over previous
//
#include <hip/hip_runtime.h>
#include <stdint.h>

#pragma clang fp contract(off)

constexpr int B_ = 1024, IN_ = 2048, H0_ = 1024, H1_ = 1024, OUT_ = 512;
constexpr int TC = 4;        // timesteps per chunk
constexpr int NCHUNK = 4;    // 16 / TC
constexpr int PQ = 512;      // K-panel width (bitwise-verified in round 16)

// Arithmetic fence: forces the f32 value to materialize — kills FMA contraction
// and reassociation across this point even under -ffp-contract=fast.
static __device__ __forceinline__ float fencef(float x) {
  asm volatile("" : "+v"(x));
  return x;
}

// ---------- transpose chunk: X[b][i][t0..t0+3] -> Xt[tt*B + b][i] (f32) ----------
__global__ void transpose_x4(const float* __restrict__ X, float* __restrict__ Xt, int t0) {
  int idx = blockIdx.x * 256 + threadIdx.x;  // b*IN + i
  int b = idx >> 11, i = idx & (IN_ - 1);
  float4 v = *(const float4*)(X + (size_t)idx * 16 + t0);  // 4 consecutive t's
  Xt[(size_t)b * IN_ + i] = v.x;
  Xt[(size_t)(B_ + b) * IN_ + i] = v.y;
  Xt[(size_t)(2 * B_ + b) * IN_ + i] = v.z;
  Xt[(size_t)(3 * B_ + b) * IN_ + i] = v.w;
}

// ---------- f32 NT GEMM, ONE 512-panel per block, double-buffered LDS ----------
// Panel p of C[M][N]: acc = sum_{k=512p..512p+511} fma(A[m,k], B[n,k], acc),
// single accumulator, ascending k, f32 FMA — bitwise-identical chain to the
// round-16..23 passing kernels. NEW: two LDS buffer sets, ONE barrier per
// K-tile (r17-r23 showed all resident waves convoy at the two per-tile
// barriers; halving the fences is the only untried lever).
// BM=128, BN=64, BK=32; 256 threads; 8x4 micro-tile; 51.2 KB LDS.
__global__ __launch_bounds__(256) void gemm_panel(
    const float* __restrict__ A, const float* __restrict__ Bw,
    float* __restrict__ ZP, size_t pstride, int Ntiles, int K, int N) {
  __shared__ float As[2][32][132];  // k-major, padded
  __shared__ float Bs[2][32][68];

  // bijective XCD swizzle (all grids here are multiples of 8)
  int bid = blockIdx.x, cpx = gridDim.x >> 3;
  int wg = (bid & 7) * cpx + (bid >> 3);
  int tpp = (gridDim.x / ((K + PQ - 1) / PQ));     // tiles per panel = Mt*Nt
  int p = wg / tpp, r = wg - p * tpp;
  int bm = r / Ntiles, bn = r - bm * Ntiles;

  int tid = threadIdx.x;
  int ra = tid >> 1, ca = (tid & 1) * 16;  // A staging: row 0..127, 16-col half
  int rb = tid >> 2, cb = (tid & 3) * 8;   // B staging: row 0..63, 8-col quarter
  int tx = tid & 15, ty = tid >> 4;        // micro-tile: cols tx*4.., rows ty*8..

  float acc[8][4] = {};   // THE panel chain accumulators (init 0, ascending k)
  const size_t rowA = (size_t)(bm * 128 + ra) * K + p * PQ;
  const size_t rowB = (size_t)(bn * 64 + rb) * K + p * PQ;

  float4 a0, a1, a2, a3, b0, b1;  // staging registers

#define LOADT(kk)                                           \
  do {                                                      \
    a0 = *(const float4*)(A + rowA + (kk) + ca);            \
    a1 = *(const float4*)(A + rowA + (kk) + ca + 4);        \
    a2 = *(const float4*)(A + rowA + (kk) + ca + 8);        \
    a3 = *(const float4*)(A + rowA + (kk) + ca + 12);       \
    b0 = *(const float4*)(Bw + rowB + (kk) + cb);           \
    b1 = *(const float4*)(Bw + rowB + (kk) + cb + 4);       \
  } while (0)

#define WRITET(buf)                                                   \
  do {                                                                \
    As[buf][ca + 0][ra] = a0.x;  As[buf][ca + 1][ra] = a0.y;          \
    As[buf][ca + 2][ra] = a0.z;  As[buf][ca + 3][ra] = a0.w;          \
    As[buf][ca + 4][ra] = a1.x;  As[buf][ca + 5][ra] = a1.y;          \
    As[buf][ca + 6][ra] = a1.z;  As[buf][ca + 7][ra] = a1.w;          \
    As[buf][ca + 8][ra] = a2.x;  As[buf][ca + 9][ra] = a2.y;          \
    As[buf][ca + 10][ra] = a2.z; As[buf][ca + 11][ra] = a2.w;         \
    As[buf][ca + 12][ra] = a3.x; As[buf][ca + 13][ra] = a3.y;         \
    As[buf][ca + 14][ra] = a3.z; As[buf][ca + 15][ra] = a3.w;         \
    Bs[buf][cb + 0][rb] = b0.x;  Bs[buf][cb + 1][rb] = b0.y;          \
    Bs[buf][cb + 2][rb] = b0.z;  Bs[buf][cb + 3][rb] = b0.w;          \
    Bs[buf][cb + 4][rb] = b1.x;  Bs[buf][cb + 5][rb] = b1.y;          \
    Bs[buf][cb + 6][rb] = b1.z;  Bs[buf][cb + 7][rb] = b1.w;          \
  } while (0)

#define COMPUTET(buf)                                                 \
  do {                                                                \
    _Pragma("unroll")                                                 \
    for (int k = 0; k < 32; ++k) {                                    \
      float ar[8], br[4];                                             \
      _Pragma("unroll")                                               \
      for (int i = 0; i < 8; ++i) ar[i] = As[buf][k][ty * 8 + i];     \
      _Pragma("unroll")                                               \
      for (int j = 0; j < 4; ++j) br[j] = Bs[buf][k][tx * 4 + j];     \
      _Pragma("unroll")                                               \
      for (int i = 0; i < 8; ++i)                                     \
        _Pragma("unroll")                                             \
        for (int j = 0; j < 4; ++j)                                   \
          acc[i][j] = __builtin_fmaf(ar[i], br[j], acc[i][j]);        \
    }                                                                 \
  } while (0)

  // prologue: stage tile 0 into buf 0
  LOADT(0);
  WRITET(0);
  __syncthreads();  // tile 0 ready
  // main loop: ONE barrier per tile.
  // iter t (tile index t = kk/32): load t, compute t-1 from buf (t-1)&1,
  // write t into buf t&1 (last read at tile t-2, protected by prev sync).
  int t = 1;
  for (int kk = 32; kk < PQ; kk += 32, ++t) {
    LOADT(kk);
    COMPUTET((t - 1) & 1);
    WRITET(t & 1);
    __syncthreads();  // tile t ready; all waves done reading buf (t-1)&1
  }
  COMPUTET((t - 1) & 1);  // last tile

#undef LOADT
#undef WRITET
#undef COMPUTET

  float* Cb = ZP + p * pstride + (size_t)(bm * 128 + ty * 8) * N + bn * 64 + tx * 4;
#pragma unroll
  for (int i = 0; i < 8; ++i)
#pragma unroll
    for (int j = 0; j < 4; ++j)
      Cb[(size_t)i * N + j] = acc[i][j];
}

// ---------- FLOAT32 LIF over TC steps + in-order panel combine, fenced ----------
// z = (((0 + P0) + P1) + ...) — bitwise-identical to round 16's creg loop.
template <int NP>
__global__ void lif_chunk(const float* __restrict__ ZP, size_t pstride,
                          const float* __restrict__ bias,
                          float* __restrict__ stC, float* __restrict__ stV,
                          float* __restrict__ stU, float* __restrict__ Sout,
                          float* __restrict__ accB, float* __restrict__ Out,
                          int ncol, int first, int last) {
  int gid = blockIdx.x * 256 + threadIdx.x;  // b*ncol + n
  int n = gid & (ncol - 1);
  float bn = bias[n];
  float c, v, u, s, acc;
  if (first) {
    c = 0.f; v = 0.f; u = 0.f; s = 0.f; acc = 0.f;
  } else {
    c = stC[gid]; v = stV[gid]; u = stU[gid];
    s = (v > 0.5f) ? 1.0f : 0.0f;              // bitwise-identical recompute
    acc = accB ? accB[gid] : 0.f;
  }
  size_t strideT = (size_t)B_ * (size_t)ncol;
#pragma unroll
  for (int tt = 0; tt < TC; ++tt) {
    float z = 0.f;
#pragma unroll
    for (int p = 0; p < NP; ++p)
      z = fencef(z + ZP[(size_t)p * pstride + (size_t)tt * strideT + gid]);
    float t1 = fencef(c * 0.5f);
    float t2 = fencef(t1 + z);
    c = fencef(t2 + bn);                       // ((c*0.5)+z)+b — np order
    float w1 = fencef(1.0f - s);
    float w2 = fencef(v * w1);
    float w3 = fencef(0.021f * s);
    float vv = fencef(w2 + w3);                // post-reset v'
    float w4 = fencef(s * 0.132f);
    float uu = fencef(u + w4);                 // post-reset u'
    float q1 = fencef(vv * vv);
    float q2 = fencef(q1 - vv);
    float q3 = fencef(q2 - uu);
    float dv = fencef(q3 + c);
    float r1 = fencef(-0.172f * vv);
    float r2 = fencef(0.529f * uu);
    float du = fencef(r1 + r2);
    v = fencef(vv + dv);
    u = fencef(uu + du);
    s = (v > 0.5f) ? 1.0f : 0.0f;
    if (Sout) Sout[(size_t)tt * strideT + gid] = s;
    acc = fencef(acc + s);                     // exact small integer
  }
  stC[gid] = c; stV[gid] = v; stU[gid] = u;
  if (accB) accB[gid] = acc;
  if (Out && last) Out[gid] = acc * 0.0625f;   // acc/16 exact
}

extern "C" void kernel_launch(void* const* d_in, const int* in_sizes, int n_in,
                              void* d_out, int out_size, void* d_ws, size_t ws_size,
                              hipStream_t stream) {
  const float* X  = (const float*)d_in[0];
  const float* W0 = (const float*)d_in[1];
  const float* b0 = (const float*)d_in[2];
  const float* W1 = (const float*)d_in[3];
  const float* b1 = (const float*)d_in[4];
  const float* W2 = (const float*)d_in[5];
  const float* b2 = (const float*)d_in[6];
  float* Out = (float*)d_out;
  char* ws = (char*)d_ws;
  constexpr size_t MB = 1024ull * 1024ull;
  // workspace layout — peak 160 MB (proven in-bounds in round 23)
  float* Xt   = (float*)(ws);               // [4096][2048] f32 = 32 MB
  float* ZP   = (float*)(ws + 32 * MB);     // 4 panels x [4096][1024] f32 = 64 MB
  float* S0c  = (float*)(ws + 96 * MB);     // [4096][1024] f32 = 16 MB
  float* S1c  = (float*)(ws + 112 * MB);    // [4096][1024] f32 = 16 MB
  float* st0c = (float*)(ws + 128 * MB);    // [1024*1024] f32 = 4 MB each
  float* st0v = (float*)(ws + 132 * MB);
  float* st0u = (float*)(ws + 136 * MB);
  float* st1c = (float*)(ws + 140 * MB);
  float* st1v = (float*)(ws + 144 * MB);
  float* st1u = (float*)(ws + 148 * MB);
  float* st2c = (float*)(ws + 152 * MB);    // [1024*512] f32 = 2 MB each
  float* st2v = (float*)(ws + 154 * MB);
  float* st2u = (float*)(ws + 156 * MB);
  float* accB = (float*)(ws + 158 * MB);    // [1024*512] f32 = 2 MB

  const size_t psH = (size_t)(TC * B_) * H0_;  // panel stride, N=1024 layers
  const size_t psO = (size_t)(TC * B_) * OUT_; // panel stride, N=512 layer

  for (int ci = 0; ci < NCHUNK; ++ci) {
    int first = (ci == 0) ? 1 : 0;
    int last = (ci == NCHUNK - 1) ? 1 : 0;
    transpose_x4<<<(B_ * IN_) / 256, 256, 0, stream>>>(X, Xt, ci * TC);
    // layer 0: K=2048 -> 4 panels; grid = 4 * 32 * 16 = 2048 blocks
    gemm_panel<<<4 * (TC * B_ / 128) * (H0_ / 64), 256, 0, stream>>>(
        Xt, W0, ZP, psH, H0_ / 64, IN_, H0_);
    lif_chunk<4><<<(B_ * H0_) / 256, 256, 0, stream>>>(
        ZP, psH, b0, st0c, st0v, st0u, S0c, nullptr, nullptr, H0_, first, 0);
    // layer 1: K=1024 -> 2 panels; grid = 2 * 32 * 16 = 1024 blocks
    gemm_panel<<<2 * (TC * B_ / 128) * (H1_ / 64), 256, 0, stream>>>(
        S0c, W1, ZP, psH, H1_ / 64, H0_, H1_);
    lif_chunk<2><<<(B_ * H1_) / 256, 256, 0, stream>>>(
        ZP, psH, b1, st1c, st1v, st1u, S1c, nullptr, nullptr, H1_, first, 0);
    // layer 2: K=1024 -> 2 panels; grid = 2 * 32 * 8 = 512 blocks
    gemm_panel<<<2 * (TC * B_ / 128) * (OUT_ / 64), 256, 0, stream>>>(
        S1c, W2, ZP, psO, OUT_ / 64, H1_, OUT_);
    lif_chunk<2><<<(B_ * OUT_) / 256, 256, 0, stream>>>(
        ZP, psO, b2, st2c, st2v, st2u, nullptr, accB, Out, OUT_, first, last);
  }
}